// Round 5
// baseline (318.062 us; speedup 1.0000x reference)
//
#include <hip/hip_runtime.h>
#include <stdint.h>

// Problem constants (fixed by the reference)
#define E_EXPERTS 8
#define D_DIM 1024
#define I_DIM 2048
#define T_TOKENS 4096
#define NSLOTS 8192                 // T * K
#define TILE 128
#define MAXPAD (NSLOTS + E_EXPERTS * TILE)   // 9216
#define TPX 9                       // tiles per XCD chunk (8*9=72 >= max 71 tiles)

#define W1_TT 4096                  // w1 64x64 transpose tiles (8 * 16 * 32)
#define W2_TT 4096                  // w2 64x64 transpose tiles
#define CX_BLOCKS 1024              // x convert blocks (4096 elems each)
#define PREP_GRID (1 + W1_TT + CX_BLOCKS)
#define NG1 (8 * TPX * (I_DIM / 128))        // 1152 gemm1 blocks
#define G1_GRID (NG1 * 5)                    // 1:4 interleave with w2 transpose

typedef __attribute__((ext_vector_type(8))) short bf16x8;
typedef __attribute__((ext_vector_type(4))) float f32x4;
typedef __attribute__((ext_vector_type(8))) unsigned short u16x8;

__device__ __forceinline__ unsigned short f2b(float f) {
  union { float f; uint32_t u; } v; v.f = f;
  uint32_t r = v.u + 0x7FFFu + ((v.u >> 16) & 1u);   // round-to-nearest-even
  return (unsigned short)(r >> 16);
}
__device__ __forceinline__ float b2f(unsigned short u) {
  union { uint32_t u; float f; } v; v.u = ((uint32_t)u) << 16; return v.f;
}

// async 16B global -> LDS (dest = wave-uniform base + lane*16)
__device__ __forceinline__ void async16(const unsigned short* g, unsigned short* l) {
  __builtin_amdgcn_global_load_lds(
      (const __attribute__((address_space(1))) void*)g,
      (__attribute__((address_space(3))) void*)l, 16, 0, 0);
}

// 64x64 transpose+cvt tile: src [E][R][C] fp32 -> dst [E][C][R] bf16.
// Load: 4x float4/thread; store: 2x ushort8 (16B)/thread; LDS 64x65 fp32.
// Bank aliasing <= 2-way on both phases (free, m136).
__device__ __forceinline__ void tile_tr64(const float* __restrict__ src,
                                          unsigned short* __restrict__ dst,
                                          int R, int C, int t, int tid,
                                          float (*lt)[65]) {
  int eid = t >> 9, tt = t & 511;             // 512 tiles per expert (both shapes)
  int ctiles = C >> 6;
  int c0 = (tt % ctiles) << 6, r0 = (tt / ctiles) << 6;
  size_t eoff = (size_t)eid * R * C;
  int tx = tid & 15, ty = tid >> 4;           // 16 x 16 loaders
#pragma unroll
  for (int q = 0; q < 4; q++) {
    float4 v = *(const float4*)(src + eoff + (size_t)(r0 + ty + q * 16) * C + c0 + tx * 4);
    lt[ty + q * 16][tx * 4 + 0] = v.x;
    lt[ty + q * 16][tx * 4 + 1] = v.y;
    lt[ty + q * 16][tx * 4 + 2] = v.z;
    lt[ty + q * 16][tx * 4 + 3] = v.w;
  }
  __syncthreads();
  int ox = tid & 7, oy = tid >> 3;            // 8 x 32 storers
#pragma unroll
  for (int q = 0; q < 2; q++) {
    int cr = oy + q * 32;
    u16x8 o;
#pragma unroll
    for (int j = 0; j < 8; j++) o[j] = f2b(lt[ox * 8 + j][cr]);
    *(u16x8*)(dst + eoff + (size_t)(c0 + cr) * R + r0 + ox * 8) = o;
  }
}

// ---- prep_a: routing (block 0) + w1 transpose-cvt + x cvt --------------------
__global__ __launch_bounds__(256) void prep_a_k(
    const float* __restrict__ x, const float* __restrict__ w1,
    const int* __restrict__ se,
    unsigned short* __restrict__ xb, unsigned short* __restrict__ w1t,
    int* __restrict__ ntiles, int* __restrict__ desc,
    int* __restrict__ tok, int* __restrict__ slot_of) {
  int b = blockIdx.x;
  int tid = threadIdx.x;

  if (b == 0) {
    __shared__ int scnt[E_EXPERTS], sbase[E_EXPERTS + 1], scur[E_EXPERTS];
    if (tid < E_EXPERTS) scnt[tid] = 0;
    __syncthreads();
    for (int s = tid; s < NSLOTS; s += 256) atomicAdd(&scnt[se[s]], 1);
    __syncthreads();
    if (tid == 0) {
      int acc = 0, nt = 0;
      for (int e = 0; e < E_EXPERTS; e++) {
        int n = scnt[e];
        sbase[e] = acc;
        scur[e] = acc;
        int pad = (n + TILE - 1) & ~(TILE - 1);
        for (int m = 0; m * TILE < pad; m++) { desc[2 * nt] = e; desc[2 * nt + 1] = acc + m * TILE; nt++; }
        acc += pad;
      }
      sbase[E_EXPERTS] = acc;
      *ntiles = nt;
    }
    __syncthreads();
    for (int e = 0; e < E_EXPERTS; e++) {
      int s0 = sbase[e] + scnt[e], s1 = sbase[e + 1];
      for (int s = s0 + tid; s < s1; s += 256) tok[s] = 0;   // pad -> token 0
    }
    for (int s = tid; s < NSLOTS; s += 256) {
      int e = se[s];
      int pos = atomicAdd(&scur[e], 1);
      tok[pos] = s >> 1;      // K=2
      slot_of[s] = pos;
    }
    return;
  }

  if (b <= W1_TT) {
    __shared__ float lt[64][65];
    tile_tr64(w1, w1t, D_DIM, I_DIM, b - 1, tid, lt);
    return;
  }

  // x fp32 -> bf16: 4096 elems per block, 4 coalesced passes
  int cb = b - 1 - W1_TT;
  int base = cb * 4096 + tid * 4;
#pragma unroll
  for (int q = 0; q < 4; q++) {
    int i = base + q * 1024;
    float4 v = *(const float4*)(x + i);
    ushort4 o;
    o.x = f2b(v.x); o.y = f2b(v.y); o.z = f2b(v.z); o.w = f2b(v.w);
    *(ushort4*)(xb + i) = o;
  }
}

// ---- GEMM core (device): 128x128 tile, BK=64, 16x16x32 bf16 MFMA -------------
template <int KLEN, int ASTR, int BSTR, int NDIM, int PHASE>
__device__ __forceinline__ void gemm_body(
    const unsigned short* __restrict__ Amat, const unsigned short* __restrict__ Bt,
    const int* __restrict__ desc, const int* __restrict__ ntiles_p,
    const int* __restrict__ tok, unsigned short* __restrict__ Hout,
    int xcd, int r, int kh_in, unsigned short* As, unsigned short* Bs) {
  int ti = xcd * TPX + r % TPX;
  int q = r / TPX;
  int nb, kh;
  if (PHASE == 1) { nb = q; kh = 0; }
  else           { kh = q & 1; nb = q >> 1; }
  (void)kh_in;
  if (ti >= *ntiles_p) return;
  int e = desc[2 * ti];
  int slot0 = desc[2 * ti + 1];

  const unsigned short* Bbase = Bt + (size_t)e * NDIM * BSTR + (size_t)nb * 128 * BSTR + kh * KLEN;

  int tid = threadIdx.x;
  int lane = tid & 63;
  int wave = tid >> 6;
  int wm = (wave >> 1) * 64, wn = (wave & 1) * 64;
  int l15 = lane & 15, quad = lane >> 4;

  f32x4 acc[4][4] = {};

  int sr = tid >> 3;                               // row base, 0..31
  int ldoff = (((lane & 7) ^ (lane >> 3)) * 8);    // swizzle-inverse content offset

  const unsigned short* arow[4];
  const unsigned short* brow[4];
#pragma unroll
  for (int p = 0; p < 4; p++) {
    int rr = sr + p * 32;
    int row = (PHASE == 1) ? tok[slot0 + rr] : (slot0 + rr);
    arow[p] = Amat + (size_t)row * ASTR + kh * KLEN + ldoff;
    brow[p] = Bbase + (size_t)rr * BSTR + ldoff;
  }

  for (int kt = 0; kt < KLEN / 64; kt++) {
    int k0 = kt * 64;
#pragma unroll
    for (int p = 0; p < 4; p++) {
      unsigned short* adst = As + (size_t)(p * 256 + wave * 64) * 8;
      unsigned short* bdst = Bs + (size_t)(p * 256 + wave * 64) * 8;
      async16(arow[p] + k0, adst);
      async16(brow[p] + k0, bdst);
    }
    __syncthreads();
#pragma unroll
    for (int ks = 0; ks < 2; ks++) {
      bf16x8 af[4], bfr[4];
#pragma unroll
      for (int i = 0; i < 4; i++) {
        int rr = wm + i * 16 + l15;
        int cc = (((ks * 4 + quad) ^ (rr & 7)) * 8);
        af[i] = *(const bf16x8*)&As[rr * 64 + cc];
      }
#pragma unroll
      for (int j = 0; j < 4; j++) {
        int rr = wn + j * 16 + l15;
        int cc = (((ks * 4 + quad) ^ (rr & 7)) * 8);
        bfr[j] = *(const bf16x8*)&Bs[rr * 64 + cc];
      }
#pragma unroll
      for (int i = 0; i < 4; i++)
#pragma unroll
        for (int j = 0; j < 4; j++)
          acc[i][j] = __builtin_amdgcn_mfma_f32_16x16x32_bf16(af[i], bfr[j], acc[i][j], 0, 0, 0);
    }
    __syncthreads();
  }

  // Epilogue. C/D frag: col = lane&15, row = quad*4 + reg  [verified m89/m91]
#pragma unroll
  for (int i = 0; i < 4; i++) {
    int slotr = slot0 + wm + i * 16 + quad * 4;
#pragma unroll
    for (int rg = 0; rg < 4; rg++) {
      int row = slotr + rg;
      size_t base = (PHASE == 1) ? (size_t)row * NDIM
                                 : ((size_t)kh * MAXPAD + row) * NDIM;
#pragma unroll
      for (int j = 0; j < 4; j++) {
        int col = nb * 128 + wn + j * 16 + l15;
        float v = acc[i][j][rg];
        if (PHASE == 1) v = v / (1.f + __expf(-v));        // silu
        Hout[base + col] = f2b(v);
      }
    }
  }
}

// ---- gemm1 fused with w2 transpose (1:4 interleave) --------------------------
// id%5==0 -> gemm block gid=id/5 (xcd = id&7 matches physical since id=5*gid,
// gid%8 -> (5*gid)%8 is a bijection); else -> w2 transpose tile.
__global__ __launch_bounds__(256) void gemm1_fused_k(
    const unsigned short* __restrict__ xb, const unsigned short* __restrict__ w1t,
    const float* __restrict__ w2, unsigned short* __restrict__ w2t,
    const int* __restrict__ desc, const int* __restrict__ ntiles_p,
    const int* __restrict__ tok, unsigned short* __restrict__ hbuf) {
  __shared__ union {
    struct { unsigned short As[128 * 64]; unsigned short Bs[128 * 64]; } g;
    float lt[64][65];
  } sm;
  int id = blockIdx.x;
  int m5 = id % 5;
  if (m5 == 0) {
    int gid = id / 5;
    gemm_body<1024, 1024, 1024, I_DIM, 1>(xb, w1t, desc, ntiles_p, tok, hbuf,
                                          id & 7, gid >> 3, 0, sm.g.As, sm.g.Bs);
  } else {
    int t = id - id / 5 - 1;
    if (t < W2_TT) tile_tr64(w2, w2t, I_DIM, D_DIM, t, threadIdx.x, sm.lt);
  }
}

__global__ __launch_bounds__(256) void gemm2_k(
    const unsigned short* __restrict__ hbuf, const unsigned short* __restrict__ w2t,
    const int* __restrict__ desc, const int* __restrict__ ntiles_p,
    const int* __restrict__ tok, unsigned short* __restrict__ ypart) {
  __shared__ unsigned short As[128 * 64];
  __shared__ unsigned short Bs[128 * 64];
  int id = blockIdx.x;
  gemm_body<1024, 2048, 2048, D_DIM, 2>(hbuf, w2t, desc, ntiles_p, tok, ypart,
                                        id & 7, id >> 3, 0, As, Bs);
}

// out[t][d] = sum_k rw[t*2+k] * (y0[slot_of[t*2+k]][d] + y1[slot_of[t*2+k]][d])
__global__ void combine_k(const unsigned short* __restrict__ y, const float* __restrict__ rw,
                          const int* __restrict__ slot_of, float* __restrict__ out) {
  int g = blockIdx.x * blockDim.x + threadIdx.x;   // T*128 threads, 8 elems each
  int t = g >> 7, dd = (g & 127) * 8;
  int s0 = slot_of[2 * t], s1 = slot_of[2 * t + 1];
  float w0 = rw[2 * t], w1 = rw[2 * t + 1];
  const unsigned short* p00 = y + (size_t)s0 * D_DIM + dd;
  const unsigned short* p01 = y + ((size_t)MAXPAD + s0) * D_DIM + dd;
  const unsigned short* p10 = y + (size_t)s1 * D_DIM + dd;
  const unsigned short* p11 = y + ((size_t)MAXPAD + s1) * D_DIM + dd;
  ushort4 a0 = *(const ushort4*)p00, a1 = *(const ushort4*)(p00 + 4);
  ushort4 b0 = *(const ushort4*)p01, b1 = *(const ushort4*)(p01 + 4);
  ushort4 c0 = *(const ushort4*)p10, c1 = *(const ushort4*)(p10 + 4);
  ushort4 d0 = *(const ushort4*)p11, d1 = *(const ushort4*)(p11 + 4);
  float4 o0, o1;
  o0.x = w0 * (b2f(a0.x) + b2f(b0.x)) + w1 * (b2f(c0.x) + b2f(d0.x));
  o0.y = w0 * (b2f(a0.y) + b2f(b0.y)) + w1 * (b2f(c0.y) + b2f(d0.y));
  o0.z = w0 * (b2f(a0.z) + b2f(b0.z)) + w1 * (b2f(c0.z) + b2f(d0.z));
  o0.w = w0 * (b2f(a0.w) + b2f(b0.w)) + w1 * (b2f(c0.w) + b2f(d0.w));
  o1.x = w0 * (b2f(a1.x) + b2f(b1.x)) + w1 * (b2f(c1.x) + b2f(d1.x));
  o1.y = w0 * (b2f(a1.y) + b2f(b1.y)) + w1 * (b2f(c1.y) + b2f(d1.y));
  o1.z = w0 * (b2f(a1.z) + b2f(b1.z)) + w1 * (b2f(c1.z) + b2f(d1.z));
  o1.w = w0 * (b2f(a1.w) + b2f(b1.w)) + w1 * (b2f(c1.w) + b2f(d1.w));
  float* op = out + (size_t)t * D_DIM + dd;
  *(float4*)op = o0;
  *(float4*)(op + 4) = o1;
}

extern "C" void kernel_launch(void* const* d_in, const int* in_sizes, int n_in,
                              void* d_out, int out_size, void* d_ws, size_t ws_size,
                              hipStream_t stream) {
  (void)in_sizes; (void)n_in; (void)ws_size; (void)out_size;
  const float* x  = (const float*)d_in[0];
  const float* rw = (const float*)d_in[1];
  const int*   se = (const int*)d_in[2];
  const float* w1 = (const float*)d_in[3];
  const float* w2 = (const float*)d_in[4];
  float* out = (float*)d_out;
  char* ws = (char*)d_ws;

  int* ntiles  = (int*)(ws + 128);
  int* desc    = (int*)(ws + 256);
  int* tok     = (int*)(ws + 4096);          // MAXPAD ints
  int* slot_of = (int*)(ws + 40960);         // NSLOTS ints
  unsigned short* xb   = (unsigned short*)(ws + 131072);              // 8.39 MB
  unsigned short* w1t  = xb + (size_t)T_TOKENS * D_DIM;               // 33.55 MB
  unsigned short* w2t  = w1t + (size_t)E_EXPERTS * D_DIM * I_DIM;     // 33.55 MB
  unsigned short* hbuf = w2t + (size_t)E_EXPERTS * D_DIM * I_DIM;     // 37.75 MB
  // ypart overlays xb+w1t (both dead after gemm1): 37.75 MB <= 41.94 MB
  unsigned short* ypart = xb;

  prep_a_k<<<PREP_GRID, 256, 0, stream>>>(x, w1, se, xb, w1t, ntiles, desc, tok, slot_of);
  gemm1_fused_k<<<G1_GRID, 256, 0, stream>>>(xb, w1t, w2, w2t, desc, ntiles, tok, hbuf);
  gemm2_k<<<8 * TPX * (D_DIM / 128) * 2, 256, 0, stream>>>(hbuf, w2t, desc, ntiles, tok, ypart);
  combine_k<<<T_TOKENS * 128 / 256, 256, 0, stream>>>(ypart, rw, slot_of, out);
}

// Round 6
// 314.434 us; speedup vs baseline: 1.0115x; 1.0115x over previous
//
#include <hip/hip_runtime.h>
#include <stdint.h>

// Problem constants (fixed by the reference)
#define E_EXPERTS 8
#define D_DIM 1024
#define I_DIM 2048
#define T_TOKENS 4096
#define NSLOTS 8192                 // T * K
#define TILE 128
#define MAXPAD (NSLOTS + E_EXPERTS * TILE)   // 9216
#define TPX 9                       // tiles per XCD chunk (8*9=72 >= max 71 tiles)

#define W1_TT 4096                  // w1 64x64 transpose tiles
#define W2_TT 4096                  // w2 64x64 transpose tiles
#define CX_BLOCKS 1024              // x convert blocks (4096 elems each)
#define PREP_GRID (1 + W1_TT + W2_TT + CX_BLOCKS)

typedef __attribute__((ext_vector_type(8))) short bf16x8;
typedef __attribute__((ext_vector_type(4))) float f32x4;
typedef __attribute__((ext_vector_type(8))) unsigned short u16x8;

__device__ __forceinline__ unsigned short f2b(float f) {
  union { float f; uint32_t u; } v; v.f = f;
  uint32_t r = v.u + 0x7FFFu + ((v.u >> 16) & 1u);   // round-to-nearest-even
  return (unsigned short)(r >> 16);
}
__device__ __forceinline__ float b2f(unsigned short u) {
  union { uint32_t u; float f; } v; v.u = ((uint32_t)u) << 16; return v.f;
}

// async 16B global -> LDS (dest = wave-uniform base + lane*16)
__device__ __forceinline__ void async16(const unsigned short* g, unsigned short* l) {
  __builtin_amdgcn_global_load_lds(
      (const __attribute__((address_space(1))) void*)g,
      (__attribute__((address_space(3))) void*)l, 16, 0, 0);
}

// 64x64 transpose+cvt tile: src [E][R][C] fp32 -> dst [E][C][R] bf16.
// Load: 4x float4/thread; store: 2x ushort8 (16B)/thread; LDS 64x65 fp32.
// Bank aliasing <= 2-way on both phases (free, m136).
__device__ __forceinline__ void tile_tr64(const float* __restrict__ src,
                                          unsigned short* __restrict__ dst,
                                          int R, int C, int t, int tid,
                                          float (*lt)[65]) {
  int eid = t >> 9, tt = t & 511;             // 512 tiles per expert (both shapes)
  int ctiles = C >> 6;
  int c0 = (tt % ctiles) << 6, r0 = (tt / ctiles) << 6;
  size_t eoff = (size_t)eid * R * C;
  int tx = tid & 15, ty = tid >> 4;           // 16 x 16 loaders
#pragma unroll
  for (int q = 0; q < 4; q++) {
    float4 v = *(const float4*)(src + eoff + (size_t)(r0 + ty + q * 16) * C + c0 + tx * 4);
    lt[ty + q * 16][tx * 4 + 0] = v.x;
    lt[ty + q * 16][tx * 4 + 1] = v.y;
    lt[ty + q * 16][tx * 4 + 2] = v.z;
    lt[ty + q * 16][tx * 4 + 3] = v.w;
  }
  __syncthreads();
  int ox = tid & 7, oy = tid >> 3;            // 8 x 32 storers
#pragma unroll
  for (int q = 0; q < 2; q++) {
    int cr = oy + q * 32;
    u16x8 o;
#pragma unroll
    for (int j = 0; j < 8; j++) o[j] = f2b(lt[ox * 8 + j][cr]);
    *(u16x8*)(dst + eoff + (size_t)(c0 + cr) * R + r0 + ox * 8) = o;
  }
}

// ---- prep: routing (block 0) + w1/w2 transpose-cvt + x cvt -------------------
__global__ __launch_bounds__(256) void prep_k(
    const float* __restrict__ x, const float* __restrict__ w1,
    const float* __restrict__ w2, const int* __restrict__ se,
    unsigned short* __restrict__ xb, unsigned short* __restrict__ w1t,
    unsigned short* __restrict__ w2t,
    int* __restrict__ ntiles, int* __restrict__ desc,
    int* __restrict__ tok, int* __restrict__ slot_of) {
  int b = blockIdx.x;
  int tid = threadIdx.x;

  if (b == 0) {
    // single-workgroup routing: count -> scan -> pad-fill + scatter
    __shared__ int scnt[E_EXPERTS], sbase[E_EXPERTS + 1], scur[E_EXPERTS];
    if (tid < E_EXPERTS) scnt[tid] = 0;
    __syncthreads();
    for (int s = tid; s < NSLOTS; s += 256) atomicAdd(&scnt[se[s]], 1);
    __syncthreads();
    if (tid == 0) {
      int acc = 0, nt = 0;
      for (int e = 0; e < E_EXPERTS; e++) {
        int n = scnt[e];
        sbase[e] = acc;
        scur[e] = acc;
        int pad = (n + TILE - 1) & ~(TILE - 1);
        for (int m = 0; m * TILE < pad; m++) { desc[2 * nt] = e; desc[2 * nt + 1] = acc + m * TILE; nt++; }
        acc += pad;
      }
      sbase[E_EXPERTS] = acc;
      *ntiles = nt;
    }
    __syncthreads();
    for (int e = 0; e < E_EXPERTS; e++) {
      int s0 = sbase[e] + scnt[e], s1 = sbase[e + 1];
      for (int s = s0 + tid; s < s1; s += 256) tok[s] = 0;   // pad -> token 0
    }
    for (int s = tid; s < NSLOTS; s += 256) {
      int e = se[s];
      int pos = atomicAdd(&scur[e], 1);
      tok[pos] = s >> 1;      // K=2
      slot_of[s] = pos;
    }
    return;
  }

  if (b <= W1_TT) {
    __shared__ float lt[64][65];
    tile_tr64(w1, w1t, D_DIM, I_DIM, b - 1, tid, lt);
    return;
  }
  if (b <= W1_TT + W2_TT) {
    __shared__ float lt2[64][65];
    tile_tr64(w2, w2t, I_DIM, D_DIM, b - 1 - W1_TT, tid, lt2);
    return;
  }

  // x fp32 -> bf16: 4096 elems per block, 4 coalesced passes
  int cb = b - 1 - W1_TT - W2_TT;
  int base = cb * 4096 + tid * 4;
#pragma unroll
  for (int q = 0; q < 4; q++) {
    int i = base + q * 1024;
    float4 v = *(const float4*)(x + i);
    ushort4 o;
    o.x = f2b(v.x); o.y = f2b(v.y); o.z = f2b(v.z); o.w = f2b(v.w);
    *(ushort4*)(xb + i) = o;
  }
}

// ---- GEMM core (device): 128x128 tile, BK=64, 16x16x32 bf16 MFMA -------------
template <int KLEN, int ASTR, int BSTR, int NDIM, int PHASE>
__device__ __forceinline__ void gemm_body(
    const unsigned short* __restrict__ Amat, const unsigned short* __restrict__ Bt,
    const int* __restrict__ desc, const int* __restrict__ ntiles_p,
    const int* __restrict__ tok, unsigned short* __restrict__ Hout,
    int xcd, int r, unsigned short* As, unsigned short* Bs) {
  int ti = xcd * TPX + r % TPX;
  int q = r / TPX;
  int nb, kh;
  if (PHASE == 1) { nb = q; kh = 0; }
  else           { kh = q & 1; nb = q >> 1; }
  if (ti >= *ntiles_p) return;
  int e = desc[2 * ti];
  int slot0 = desc[2 * ti + 1];

  const unsigned short* Bbase = Bt + (size_t)e * NDIM * BSTR + (size_t)nb * 128 * BSTR + kh * KLEN;

  int tid = threadIdx.x;
  int lane = tid & 63;
  int wave = tid >> 6;
  int wm = (wave >> 1) * 64, wn = (wave & 1) * 64;
  int l15 = lane & 15, quad = lane >> 4;

  f32x4 acc[4][4] = {};

  int sr = tid >> 3;                               // row base, 0..31
  int ldoff = (((lane & 7) ^ (lane >> 3)) * 8);    // swizzle-inverse content offset

  const unsigned short* arow[4];
  const unsigned short* brow[4];
#pragma unroll
  for (int p = 0; p < 4; p++) {
    int rr = sr + p * 32;
    int row = (PHASE == 1) ? tok[slot0 + rr] : (slot0 + rr);
    arow[p] = Amat + (size_t)row * ASTR + kh * KLEN + ldoff;
    brow[p] = Bbase + (size_t)rr * BSTR + ldoff;
  }

  for (int kt = 0; kt < KLEN / 64; kt++) {
    int k0 = kt * 64;
#pragma unroll
    for (int p = 0; p < 4; p++) {
      unsigned short* adst = As + (size_t)(p * 256 + wave * 64) * 8;
      unsigned short* bdst = Bs + (size_t)(p * 256 + wave * 64) * 8;
      async16(arow[p] + k0, adst);
      async16(brow[p] + k0, bdst);
    }
    __syncthreads();
#pragma unroll
    for (int ks = 0; ks < 2; ks++) {
      bf16x8 af[4], bfr[4];
#pragma unroll
      for (int i = 0; i < 4; i++) {
        int rr = wm + i * 16 + l15;
        int cc = (((ks * 4 + quad) ^ (rr & 7)) * 8);
        af[i] = *(const bf16x8*)&As[rr * 64 + cc];
      }
#pragma unroll
      for (int j = 0; j < 4; j++) {
        int rr = wn + j * 16 + l15;
        int cc = (((ks * 4 + quad) ^ (rr & 7)) * 8);
        bfr[j] = *(const bf16x8*)&Bs[rr * 64 + cc];
      }
#pragma unroll
      for (int i = 0; i < 4; i++)
#pragma unroll
        for (int j = 0; j < 4; j++)
          acc[i][j] = __builtin_amdgcn_mfma_f32_16x16x32_bf16(af[i], bfr[j], acc[i][j], 0, 0, 0);
    }
    __syncthreads();
  }

  // Epilogue. C/D frag: col = lane&15, row = quad*4 + reg  [verified m89/m91]
#pragma unroll
  for (int i = 0; i < 4; i++) {
    int slotr = slot0 + wm + i * 16 + quad * 4;
#pragma unroll
    for (int rg = 0; rg < 4; rg++) {
      int row = slotr + rg;
      size_t base = (PHASE == 1) ? (size_t)row * NDIM
                                 : ((size_t)kh * MAXPAD + row) * NDIM;
#pragma unroll
      for (int j = 0; j < 4; j++) {
        int col = nb * 128 + wn + j * 16 + l15;
        float v = acc[i][j][rg];
        if (PHASE == 1) v = v / (1.f + __expf(-v));        // silu
        Hout[base + col] = f2b(v);
      }
    }
  }
}

__global__ __launch_bounds__(256) void gemm1_k(
    const unsigned short* __restrict__ xb, const unsigned short* __restrict__ w1t,
    const int* __restrict__ desc, const int* __restrict__ ntiles_p,
    const int* __restrict__ tok, unsigned short* __restrict__ hbuf) {
  __shared__ unsigned short As[128 * 64];
  __shared__ unsigned short Bs[128 * 64];
  int id = blockIdx.x;
  gemm_body<1024, 1024, 1024, I_DIM, 1>(xb, w1t, desc, ntiles_p, tok, hbuf,
                                        id & 7, id >> 3, As, Bs);
}

__global__ __launch_bounds__(256) void gemm2_k(
    const unsigned short* __restrict__ hbuf, const unsigned short* __restrict__ w2t,
    const int* __restrict__ desc, const int* __restrict__ ntiles_p,
    const int* __restrict__ tok, unsigned short* __restrict__ ypart) {
  __shared__ unsigned short As[128 * 64];
  __shared__ unsigned short Bs[128 * 64];
  int id = blockIdx.x;
  gemm_body<1024, 2048, 2048, D_DIM, 2>(hbuf, w2t, desc, ntiles_p, tok, ypart,
                                        id & 7, id >> 3, As, Bs);
}

// out[t][d] = sum_k rw[t*2+k] * (y0[slot_of[t*2+k]][d] + y1[slot_of[t*2+k]][d])
__global__ void combine_k(const unsigned short* __restrict__ y, const float* __restrict__ rw,
                          const int* __restrict__ slot_of, float* __restrict__ out) {
  int g = blockIdx.x * blockDim.x + threadIdx.x;   // T*128 threads, 8 elems each
  int t = g >> 7, dd = (g & 127) * 8;
  int s0 = slot_of[2 * t], s1 = slot_of[2 * t + 1];
  float w0 = rw[2 * t], w1 = rw[2 * t + 1];
  const unsigned short* p00 = y + (size_t)s0 * D_DIM + dd;
  const unsigned short* p01 = y + ((size_t)MAXPAD + s0) * D_DIM + dd;
  const unsigned short* p10 = y + (size_t)s1 * D_DIM + dd;
  const unsigned short* p11 = y + ((size_t)MAXPAD + s1) * D_DIM + dd;
  ushort4 a0 = *(const ushort4*)p00, a1 = *(const ushort4*)(p00 + 4);
  ushort4 b0 = *(const ushort4*)p01, b1 = *(const ushort4*)(p01 + 4);
  ushort4 c0 = *(const ushort4*)p10, c1 = *(const ushort4*)(p10 + 4);
  ushort4 d0 = *(const ushort4*)p11, d1 = *(const ushort4*)(p11 + 4);
  float4 o0, o1;
  o0.x = w0 * (b2f(a0.x) + b2f(b0.x)) + w1 * (b2f(c0.x) + b2f(d0.x));
  o0.y = w0 * (b2f(a0.y) + b2f(b0.y)) + w1 * (b2f(c0.y) + b2f(d0.y));
  o0.z = w0 * (b2f(a0.z) + b2f(b0.z)) + w1 * (b2f(c0.z) + b2f(d0.z));
  o0.w = w0 * (b2f(a0.w) + b2f(b0.w)) + w1 * (b2f(c0.w) + b2f(d0.w));
  o1.x = w0 * (b2f(a1.x) + b2f(b1.x)) + w1 * (b2f(c1.x) + b2f(d1.x));
  o1.y = w0 * (b2f(a1.y) + b2f(b1.y)) + w1 * (b2f(c1.y) + b2f(d1.y));
  o1.z = w0 * (b2f(a1.z) + b2f(b1.z)) + w1 * (b2f(c1.z) + b2f(d1.z));
  o1.w = w0 * (b2f(a1.w) + b2f(b1.w)) + w1 * (b2f(c1.w) + b2f(d1.w));
  float* op = out + (size_t)t * D_DIM + dd;
  *(float4*)op = o0;
  *(float4*)(op + 4) = o1;
}

extern "C" void kernel_launch(void* const* d_in, const int* in_sizes, int n_in,
                              void* d_out, int out_size, void* d_ws, size_t ws_size,
                              hipStream_t stream) {
  (void)in_sizes; (void)n_in; (void)ws_size; (void)out_size;
  const float* x  = (const float*)d_in[0];
  const float* rw = (const float*)d_in[1];
  const int*   se = (const int*)d_in[2];
  const float* w1 = (const float*)d_in[3];
  const float* w2 = (const float*)d_in[4];
  float* out = (float*)d_out;
  char* ws = (char*)d_ws;

  int* ntiles  = (int*)(ws + 128);
  int* desc    = (int*)(ws + 256);
  int* tok     = (int*)(ws + 4096);          // MAXPAD ints
  int* slot_of = (int*)(ws + 40960);         // NSLOTS ints
  unsigned short* xb   = (unsigned short*)(ws + 131072);              // 8.39 MB
  unsigned short* w1t  = xb + (size_t)T_TOKENS * D_DIM;               // 33.55 MB
  unsigned short* w2t  = w1t + (size_t)E_EXPERTS * D_DIM * I_DIM;     // 33.55 MB
  unsigned short* hbuf = w2t + (size_t)E_EXPERTS * D_DIM * I_DIM;     // 37.75 MB
  // ypart overlays xb+w1t (both dead after gemm1): 37.75 MB <= 41.94 MB
  unsigned short* ypart = xb;

  prep_k<<<PREP_GRID, 256, 0, stream>>>(x, w1, w2, se, xb, w1t, w2t,
                                        ntiles, desc, tok, slot_of);
  gemm1_k<<<8 * TPX * (I_DIM / 128), 256, 0, stream>>>(xb, w1t, desc, ntiles, tok, hbuf);
  gemm2_k<<<8 * TPX * (D_DIM / 128) * 2, 256, 0, stream>>>(hbuf, w2t, desc, ntiles, tok, ypart);
  combine_k<<<T_TOKENS * 128 / 256, 256, 0, stream>>>(ypart, rw, slot_of, out);
}

// Round 7
// 309.626 us; speedup vs baseline: 1.0272x; 1.0155x over previous
//
#include <hip/hip_runtime.h>
#include <stdint.h>

// Problem constants (fixed by the reference)
#define E_EXPERTS 8
#define D_DIM 1024
#define I_DIM 2048
#define T_TOKENS 4096
#define NSLOTS 8192                 // T * K
#define TILE 128
#define MAXPAD (NSLOTS + E_EXPERTS * TILE)   // 9216
#define TPX 9                       // tiles per XCD chunk (8*9=72 >= max 71 tiles)

#define W1_TT 4096                  // w1 64x64 transpose tiles
#define W2_TT 4096                  // w2 64x64 transpose tiles
#define CX_BLOCKS 1024              // x convert blocks (4096 elems each)
#define PREP_GRID (1 + W1_TT + W2_TT + CX_BLOCKS)

typedef __attribute__((ext_vector_type(8))) short bf16x8;
typedef __attribute__((ext_vector_type(4))) float f32x4;
typedef __attribute__((ext_vector_type(8))) unsigned short u16x8;

__device__ __forceinline__ unsigned short f2b(float f) {
  union { float f; uint32_t u; } v; v.f = f;
  uint32_t r = v.u + 0x7FFFu + ((v.u >> 16) & 1u);   // round-to-nearest-even
  return (unsigned short)(r >> 16);
}
__device__ __forceinline__ float b2f(unsigned short u) {
  union { uint32_t u; float f; } v; v.u = ((uint32_t)u) << 16; return v.f;
}

// async 16B global -> LDS (dest = wave-uniform base + lane*16)
__device__ __forceinline__ void async16(const unsigned short* g, unsigned short* l) {
  __builtin_amdgcn_global_load_lds(
      (const __attribute__((address_space(1))) void*)g,
      (__attribute__((address_space(3))) void*)l, 16, 0, 0);
}

// s_waitcnt imm: vmcnt[3:0|15:14], expcnt[6:4]=7 (ignore), lgkmcnt[11:8]=0xF (ignore)
#define WAITVM0() __builtin_amdgcn_s_waitcnt(0x0F70)

// 64x64 transpose+cvt tile: src [E][R][C] fp32 -> dst [E][C][R] bf16.
__device__ __forceinline__ void tile_tr64(const float* __restrict__ src,
                                          unsigned short* __restrict__ dst,
                                          int R, int C, int t, int tid,
                                          float (*lt)[65]) {
  int eid = t >> 9, tt = t & 511;             // 512 tiles per expert (both shapes)
  int ctiles = C >> 6;
  int c0 = (tt % ctiles) << 6, r0 = (tt / ctiles) << 6;
  size_t eoff = (size_t)eid * R * C;
  int tx = tid & 15, ty = tid >> 4;           // 16 x 16 loaders
#pragma unroll
  for (int q = 0; q < 4; q++) {
    float4 v = *(const float4*)(src + eoff + (size_t)(r0 + ty + q * 16) * C + c0 + tx * 4);
    lt[ty + q * 16][tx * 4 + 0] = v.x;
    lt[ty + q * 16][tx * 4 + 1] = v.y;
    lt[ty + q * 16][tx * 4 + 2] = v.z;
    lt[ty + q * 16][tx * 4 + 3] = v.w;
  }
  __syncthreads();
  int ox = tid & 7, oy = tid >> 3;            // 8 x 32 storers
#pragma unroll
  for (int q = 0; q < 2; q++) {
    int cr = oy + q * 32;
    u16x8 o;
#pragma unroll
    for (int j = 0; j < 8; j++) o[j] = f2b(lt[ox * 8 + j][cr]);
    *(u16x8*)(dst + eoff + (size_t)(c0 + cr) * R + r0 + ox * 8) = o;
  }
}

// ---- prep: routing (block 0) + w1/w2 transpose-cvt + x cvt -------------------
__global__ __launch_bounds__(256) void prep_k(
    const float* __restrict__ x, const float* __restrict__ w1,
    const float* __restrict__ w2, const int* __restrict__ se,
    unsigned short* __restrict__ xb, unsigned short* __restrict__ w1t,
    unsigned short* __restrict__ w2t,
    int* __restrict__ ntiles, int* __restrict__ desc,
    int* __restrict__ tok, int* __restrict__ slot_of) {
  int b = blockIdx.x;
  int tid = threadIdx.x;

  if (b == 0) {
    __shared__ int scnt[E_EXPERTS], sbase[E_EXPERTS + 1], scur[E_EXPERTS];
    if (tid < E_EXPERTS) scnt[tid] = 0;
    __syncthreads();
    for (int s = tid; s < NSLOTS; s += 256) atomicAdd(&scnt[se[s]], 1);
    __syncthreads();
    if (tid == 0) {
      int acc = 0, nt = 0;
      for (int e = 0; e < E_EXPERTS; e++) {
        int n = scnt[e];
        sbase[e] = acc;
        scur[e] = acc;
        int pad = (n + TILE - 1) & ~(TILE - 1);
        for (int m = 0; m * TILE < pad; m++) { desc[2 * nt] = e; desc[2 * nt + 1] = acc + m * TILE; nt++; }
        acc += pad;
      }
      sbase[E_EXPERTS] = acc;
      *ntiles = nt;
    }
    __syncthreads();
    for (int e = 0; e < E_EXPERTS; e++) {
      int s0 = sbase[e] + scnt[e], s1 = sbase[e + 1];
      for (int s = s0 + tid; s < s1; s += 256) tok[s] = 0;   // pad -> token 0
    }
    for (int s = tid; s < NSLOTS; s += 256) {
      int e = se[s];
      int pos = atomicAdd(&scur[e], 1);
      tok[pos] = s >> 1;      // K=2
      slot_of[s] = pos;
    }
    return;
  }

  if (b <= W1_TT) {
    __shared__ float lt[64][65];
    tile_tr64(w1, w1t, D_DIM, I_DIM, b - 1, tid, lt);
    return;
  }
  if (b <= W1_TT + W2_TT) {
    __shared__ float lt2[64][65];
    tile_tr64(w2, w2t, I_DIM, D_DIM, b - 1 - W1_TT, tid, lt2);
    return;
  }

  // x fp32 -> bf16: 4096 elems per block, 4 coalesced passes
  int cb = b - 1 - W1_TT - W2_TT;
  int base = cb * 4096 + tid * 4;
#pragma unroll
  for (int q = 0; q < 4; q++) {
    int i = base + q * 1024;
    float4 v = *(const float4*)(x + i);
    ushort4 o;
    o.x = f2b(v.x); o.y = f2b(v.y); o.z = f2b(v.z); o.w = f2b(v.w);
    *(ushort4*)(xb + i) = o;
  }
}

// ---- pipelined GEMM: 128x128 tile, BK=32, double-buffered LDS (2x8KB x2) -----
// k-loop: [wait own vmcnt(0)] [s_barrier] [issue next-iter loads] [frags+MFMA]
// LDS layout per buf: [128 rows][4 chunks][8 bf16]; slot s=(row*4+cpos) holds
// global chunk (cpos ^ ((row>>1)&3)) -> frag reads are exactly 2-way (free).
template <int KLEN, int ASTR, int BSTR, int NDIM, int PHASE>
__global__ __launch_bounds__(256) void gemm_k(
    const unsigned short* __restrict__ Amat, const unsigned short* __restrict__ Bt,
    const int* __restrict__ desc, const int* __restrict__ ntiles_p,
    const int* __restrict__ tok, unsigned short* __restrict__ Hout) {
  __shared__ unsigned short As[2][4096];
  __shared__ unsigned short Bs[2][4096];

  int id = blockIdx.x;
  int xcd = id & 7, r = id >> 3;
  int ti = xcd * TPX + r % TPX;
  int q = r / TPX;
  int nb, kh;
  if (PHASE == 1) { nb = q; kh = 0; }
  else           { kh = q & 1; nb = q >> 1; }
  if (ti >= *ntiles_p) return;
  int e = desc[2 * ti];
  int slot0 = desc[2 * ti + 1];

  const unsigned short* Bbase = Bt + (size_t)e * NDIM * BSTR + (size_t)nb * 128 * BSTR + kh * KLEN;

  int tid = threadIdx.x;
  int lane = tid & 63;
  int wave = tid >> 6;
  int wm = (wave >> 1) * 64, wn = (wave & 1) * 64;
  int l15 = lane & 15, quad = lane >> 4;

  f32x4 acc[4][4] = {};

  // per-lane staging constants: slot s = p*256 + wave*64 + lane
  const unsigned short* arow[2];
  const unsigned short* brow[2];
  int dsl[2];
#pragma unroll
  for (int p = 0; p < 2; p++) {
    int s = p * 256 + wave * 64 + lane;
    int row = s >> 2, cpos = s & 3;
    int cc = cpos ^ ((row >> 1) & 3);
    int ar = (PHASE == 1) ? tok[slot0 + row] : (slot0 + row);
    arow[p] = Amat + (size_t)ar * ASTR + (size_t)kh * KLEN + cc * 8;
    brow[p] = Bbase + (size_t)row * BSTR + cc * 8;
    dsl[p] = (p * 256 + wave * 64) * 8;       // wave-uniform LDS base (elems)
  }

  // prologue: issue iter-0 loads into buf 0
#pragma unroll
  for (int p = 0; p < 2; p++) {
    async16(arow[p], &As[0][dsl[p]]);
    async16(brow[p], &Bs[0][dsl[p]]);
  }

  const int NIT = KLEN / 32;
#pragma unroll 2
  for (int kt = 0; kt < NIT; kt++) {
    int cur = kt & 1, nxt = cur ^ 1;
    WAITVM0();                          // own cur-buf loads (issued last iter) landed
    __builtin_amdgcn_s_barrier();       // all waves landed + done reading nxt's old data
    if (kt + 1 < NIT) {
      int k0 = (kt + 1) * 32;
#pragma unroll
      for (int p = 0; p < 2; p++) {
        async16(arow[p] + k0, &As[nxt][dsl[p]]);
        async16(brow[p] + k0, &Bs[nxt][dsl[p]]);
      }
    }
    bf16x8 af[4], bfr[4];
#pragma unroll
    for (int i = 0; i < 4; i++) {
      int rr = wm + i * 16 + l15;
      af[i] = *(const bf16x8*)&As[cur][rr * 32 + ((quad ^ ((rr >> 1) & 3)) * 8)];
    }
#pragma unroll
    for (int j = 0; j < 4; j++) {
      int rr = wn + j * 16 + l15;
      bfr[j] = *(const bf16x8*)&Bs[cur][rr * 32 + ((quad ^ ((rr >> 1) & 3)) * 8)];
    }
#pragma unroll
    for (int i = 0; i < 4; i++)
#pragma unroll
      for (int j = 0; j < 4; j++)
        acc[i][j] = __builtin_amdgcn_mfma_f32_16x16x32_bf16(af[i], bfr[j], acc[i][j], 0, 0, 0);
  }

  // Epilogue. C/D frag: col = lane&15, row = quad*4 + reg  [verified m89/m91]
#pragma unroll
  for (int i = 0; i < 4; i++) {
    int slotr = slot0 + wm + i * 16 + quad * 4;
#pragma unroll
    for (int rg = 0; rg < 4; rg++) {
      int row = slotr + rg;
      size_t base = (PHASE == 1) ? (size_t)row * NDIM
                                 : ((size_t)kh * MAXPAD + row) * NDIM;
#pragma unroll
      for (int j = 0; j < 4; j++) {
        int col = nb * 128 + wn + j * 16 + l15;
        float v = acc[i][j][rg];
        if (PHASE == 1) v = v / (1.f + __expf(-v));        // silu
        Hout[base + col] = f2b(v);
      }
    }
  }
}

// out[t][d] = sum_k rw[t*2+k] * (y0[slot_of[t*2+k]][d] + y1[slot_of[t*2+k]][d])
__global__ void combine_k(const unsigned short* __restrict__ y, const float* __restrict__ rw,
                          const int* __restrict__ slot_of, float* __restrict__ out) {
  int g = blockIdx.x * blockDim.x + threadIdx.x;   // T*128 threads, 8 elems each
  int t = g >> 7, dd = (g & 127) * 8;
  int s0 = slot_of[2 * t], s1 = slot_of[2 * t + 1];
  float w0 = rw[2 * t], w1 = rw[2 * t + 1];
  const unsigned short* p00 = y + (size_t)s0 * D_DIM + dd;
  const unsigned short* p01 = y + ((size_t)MAXPAD + s0) * D_DIM + dd;
  const unsigned short* p10 = y + (size_t)s1 * D_DIM + dd;
  const unsigned short* p11 = y + ((size_t)MAXPAD + s1) * D_DIM + dd;
  ushort4 a0 = *(const ushort4*)p00, a1 = *(const ushort4*)(p00 + 4);
  ushort4 b0 = *(const ushort4*)p01, b1 = *(const ushort4*)(p01 + 4);
  ushort4 c0 = *(const ushort4*)p10, c1 = *(const ushort4*)(p10 + 4);
  ushort4 d0 = *(const ushort4*)p11, d1 = *(const ushort4*)(p11 + 4);
  float4 o0, o1;
  o0.x = w0 * (b2f(a0.x) + b2f(b0.x)) + w1 * (b2f(c0.x) + b2f(d0.x));
  o0.y = w0 * (b2f(a0.y) + b2f(b0.y)) + w1 * (b2f(c0.y) + b2f(d0.y));
  o0.z = w0 * (b2f(a0.z) + b2f(b0.z)) + w1 * (b2f(c0.z) + b2f(d0.z));
  o0.w = w0 * (b2f(a0.w) + b2f(b0.w)) + w1 * (b2f(c0.w) + b2f(d0.w));
  o1.x = w0 * (b2f(a1.x) + b2f(b1.x)) + w1 * (b2f(c1.x) + b2f(d1.x));
  o1.y = w0 * (b2f(a1.y) + b2f(b1.y)) + w1 * (b2f(c1.y) + b2f(d1.y));
  o1.z = w0 * (b2f(a1.z) + b2f(b1.z)) + w1 * (b2f(c1.z) + b2f(d1.z));
  o1.w = w0 * (b2f(a1.w) + b2f(b1.w)) + w1 * (b2f(c1.w) + b2f(d1.w));
  float* op = out + (size_t)t * D_DIM + dd;
  *(float4*)op = o0;
  *(float4*)(op + 4) = o1;
}

extern "C" void kernel_launch(void* const* d_in, const int* in_sizes, int n_in,
                              void* d_out, int out_size, void* d_ws, size_t ws_size,
                              hipStream_t stream) {
  (void)in_sizes; (void)n_in; (void)ws_size; (void)out_size;
  const float* x  = (const float*)d_in[0];
  const float* rw = (const float*)d_in[1];
  const int*   se = (const int*)d_in[2];
  const float* w1 = (const float*)d_in[3];
  const float* w2 = (const float*)d_in[4];
  float* out = (float*)d_out;
  char* ws = (char*)d_ws;

  int* ntiles  = (int*)(ws + 128);
  int* desc    = (int*)(ws + 256);
  int* tok     = (int*)(ws + 4096);          // MAXPAD ints
  int* slot_of = (int*)(ws + 40960);         // NSLOTS ints
  unsigned short* xb   = (unsigned short*)(ws + 131072);              // 8.39 MB
  unsigned short* w1t  = xb + (size_t)T_TOKENS * D_DIM;               // 33.55 MB
  unsigned short* w2t  = w1t + (size_t)E_EXPERTS * D_DIM * I_DIM;     // 33.55 MB
  unsigned short* hbuf = w2t + (size_t)E_EXPERTS * D_DIM * I_DIM;     // 37.75 MB
  // ypart overlays xb+w1t (both dead after gemm1): 37.75 MB <= 41.94 MB
  unsigned short* ypart = xb;

  prep_k<<<PREP_GRID, 256, 0, stream>>>(x, w1, w2, se, xb, w1t, w2t,
                                        ntiles, desc, tok, slot_of);
  gemm_k<1024, 1024, 1024, I_DIM, 1><<<8 * TPX * (I_DIM / 128), 256, 0, stream>>>(
      xb, w1t, desc, ntiles, tok, hbuf);
  gemm_k<1024, 2048, 2048, D_DIM, 2><<<8 * TPX * (D_DIM / 128) * 2, 256, 0, stream>>>(
      hbuf, w2t, desc, ntiles, tok, ypart);
  combine_k<<<T_TOKENS * 128 / 256, 256, 0, stream>>>(ypart, rw, slot_of, out);
}